// Round 5
// baseline (304.951 us; speedup 1.0000x reference)
//
#include <hip/hip_runtime.h>
#include <hip/hip_cooperative_groups.h>

#define NPART 4096
#define NBATCH 2
#define MAXC 128
#define NBLK 512  // 256 blocks per batch; 32KB LDS -> >=4 blocks/CU capacity

namespace cg = cooperative_groups;

// ---------------------------------------------------------------------------
// Single cooperative kernel, phases separated by grid.sync():
//  ph0: partial min/max (blocks 0..31)
//  ph1: every block replays final bounds math (f32, verified bit-exact)
//  ph2: cell ids for this block's 16 particles + zero rank counters
//  ph3: stable-rank partial counts (b, ic, jc) tiles, int atomics
//  ph4: scatter-gather: thread of particle i writes idxs/locs/data/slocs at r
//  ph5: neighbor scan: 16 rows/block, 4 rows/wave, half-batch LDS staging
// ---------------------------------------------------------------------------
__global__ __launch_bounds__(256, 2) void fused_kernel(
    const float* __restrict__ locs, const float* __restrict__ data,
    float* __restrict__ out_idxs, float* __restrict__ out_nbr,
    float* __restrict__ out_locs, float* __restrict__ out_data,
    float* __restrict__ pmin, float* __restrict__ pmax,
    int* __restrict__ cell_ids, int* __restrict__ rank,
    float4* __restrict__ slocs) {
  cg::grid_group grid = cg::this_grid();
  __shared__ __align__(16) char smem[32768];
  const int bx = blockIdx.x;
  const int tid = threadIdx.x;
  const int b = bx >> 8;  // batch of this block (0..1)

  // ---- phase 0: partial min/max; blocks 0..31 = (batch, chunk-of-256) ----
  if (bx < 32) {
    int pb = bx >> 4;
    int chunk = bx & 15;
    float* smn = (float*)smem;        // [3][256]
    float* smx = smn + 3 * 256;       // [3][256]
    int i = chunk * 256 + tid;
    const float* src = locs + ((size_t)pb * NPART + i) * 3;
    float x = src[0], y = src[1], z = src[2];
    smn[0 * 256 + tid] = x; smn[1 * 256 + tid] = y; smn[2 * 256 + tid] = z;
    smx[0 * 256 + tid] = x; smx[1 * 256 + tid] = y; smx[2 * 256 + tid] = z;
    __syncthreads();
    for (int s = 128; s > 0; s >>= 1) {
      if (tid < s) {
        for (int d = 0; d < 3; d++) {
          smn[d * 256 + tid] = fminf(smn[d * 256 + tid], smn[d * 256 + tid + s]);
          smx[d * 256 + tid] = fmaxf(smx[d * 256 + tid], smx[d * 256 + tid + s]);
        }
      }
      __syncthreads();
    }
    if (tid == 0) {
      for (int d = 0; d < 3; d++) {
        pmin[bx * 3 + d] = smn[d * 256];
        pmax[bx * 3 + d] = smx[d * 256];
      }
    }
  }
  grid.sync();

  // ---- phase 1: every block computes its batch's bounds into LDS ----
  // (f32 arithmetic schedule verified bit-exact vs reference)
  float* sb_lower = (float*)(smem + 8192);  // [3]
  int* sb_gdi = (int*)(smem + 8192 + 16);   // [3]
  if (tid == 0) {
    for (int d = 0; d < 3; d++) {
      float lo = 1e30f, up = -1e30f;
      for (int k = 0; k < 16; k++) {
        lo = fminf(lo, pmin[(b * 16 + k) * 3 + d]);
        up = fmaxf(up, pmax[(b * 16 + k) * 3 + d]);
      }
      float t = (up - lo) / 0.1f;              // fp32 IEEE div
      t = fminf(fmaxf(t, 0.0f), 96.0f);        // clip to [0, MAX_GRID_DIM]
      float gdim = ceilf(t);
      float ctr = (lo + up) * 0.5f;
      float l2 = ctr - ((gdim * 0.1f) * 0.5f);
      float g = fmaxf(gdim, 1.0f);
      sb_lower[d] = l2;
      sb_gdi[d] = (int)g;
    }
  }
  __syncthreads();

  // ---- phase 2: cell ids for this block's 16 particles + zero ranks ----
  if (tid < 16) {
    int p = bx * 16 + tid;  // global particle index [0, 8192); batch = bx>>8
    rank[p] = 0;
    int c[3];
    for (int d = 0; d < 3; d++) {
      float v = locs[(size_t)p * 3 + d];
      float cf = floorf((v - sb_lower[d]) / 0.1f);
      float gdf = (float)sb_gdi[d];
      cf = fminf(fmaxf(cf, 0.0f), gdf - 1.0f);
      c[d] = (int)cf;
    }
    cell_ids[p] = (c[0] * sb_gdi[1] + c[1]) * sb_gdi[2] + c[2];
  }
  grid.sync();

  // ---- phase 3: stable-rank partial counts ----
  {
    int ic = (bx >> 4) & 15;
    int jc = bx & 15;
    int* scj = (int*)smem;  // 256 ints (distinct from bounds @8192)
    scj[tid] = cell_ids[b * NPART + jc * 256 + tid];
    int ci = cell_ids[b * NPART + ic * 256 + tid];
    __syncthreads();
    int cnt = 0;
    if (jc < ic) {
#pragma unroll 8
      for (int j = 0; j < 256; j++) cnt += (scj[j] <= ci);
    } else if (jc > ic) {
#pragma unroll 8
      for (int j = 0; j < 256; j++) cnt += (scj[j] < ci);
    } else {
#pragma unroll 8
      for (int j = 0; j < 256; j++) {
        int cj = scj[j];
        cnt += (cj < ci) || (cj == ci && j < tid);
      }
    }
    atomicAdd(&rank[b * NPART + ic * 256 + tid], cnt);
  }
  grid.sync();

  // ---- phase 4: scatter-gather (blocks 0..31; thread = particle p) ----
  if (bx < 32) {
    int p = bx * 256 + tid;  // [0, 8192)
    int pb = p >> 12;
    int i = p & (NPART - 1);
    int r = rank[p];
    const float* src = locs + (size_t)p * 3;
    float x = src[0], y = src[1], z = src[2];
    // sq = (x*x + y*y) + z*z, rn mul/add (numpy materializes l*l first: no fma)
    float sq = __fadd_rn(__fadd_rn(__fmul_rn(x, x), __fmul_rn(y, y)),
                         __fmul_rn(z, z));
    size_t dst = (size_t)pb * NPART + r;
    out_idxs[dst] = (float)i;
    out_locs[dst * 3 + 0] = x;
    out_locs[dst * 3 + 1] = y;
    out_locs[dst * 3 + 2] = z;
    slocs[dst] = make_float4(x, y, z, sq);
    const float4* dsrc = (const float4*)(data + (size_t)p * 16);
    float4* ddst = (float4*)(out_data + dst * 16);
    for (int k = 0; k < 4; k++) ddst[k] = dsrc[k];
  }
  grid.sync();

  // ---- phase 5: neighbor lists. 16 rows/block, 4 rows/wave, 2 half-stages.
  //   dot = fma(z·z', fma(y·y', rn(x·x')))   (verified bit-exact)
  //   d2  = rn(sq_n + sq_m) - rn(2·dot); hit = d2 <= 0.01f
  {
    float4* sl = (float4*)smem;  // 2048 entries = 32 KB
    int wave = tid >> 6, lane = tid & 63;
    int kb = bx & 255;
    int row0 = kb * 16 + wave * 4;
    const float4* sb = slocs + (size_t)b * NPART;
    float4 me0 = sb[row0 + 0];
    float4 me1 = sb[row0 + 1];
    float4 me2 = sb[row0 + 2];
    float4 me3 = sb[row0 + 3];
    float* r0 = out_nbr + ((size_t)b * NPART + row0) * MAXC;
    float* r1 = r0 + MAXC;
    float* r2 = r1 + MAXC;
    float* r3 = r2 + MAXC;
    int c0 = 0, c1 = 0, c2 = 0, c3 = 0;
    unsigned long long lmask = (1ull << lane) - 1ull;
    for (int half = 0; half < 2; half++) {
      int hbase = half * 2048;
      __syncthreads();
      for (int j = tid; j < 2048; j += 256) sl[j] = sb[hbase + j];
      __syncthreads();
      for (int base = 0; base < 2048; base += 64) {
        float4 o = sl[base + lane];
        float fm = (float)(hbase + base + lane);
#define DO_ROW(ME, CN, RP)                                                  \
        {                                                                   \
          float dot = __fmaf_rn(ME.z, o.z,                                  \
                       __fmaf_rn(ME.y, o.y, __fmul_rn(ME.x, o.x)));         \
          float d2 = __fsub_rn(__fadd_rn(ME.w, o.w), __fmul_rn(2.0f, dot)); \
          bool hit = d2 <= 0.01f;                                           \
          unsigned long long bal = __ballot(hit);                           \
          int pos = CN + __popcll(bal & lmask);                             \
          if (hit && pos < MAXC) RP[pos] = fm;                              \
          CN += __popcll(bal);                                              \
        }
        DO_ROW(me0, c0, r0)
        DO_ROW(me1, c1, r1)
        DO_ROW(me2, c2, r2)
        DO_ROW(me3, c3, r3)
#undef DO_ROW
      }
    }
    for (int q = min(c0, MAXC) + lane; q < MAXC; q += 64) r0[q] = -1.0f;
    for (int q = min(c1, MAXC) + lane; q < MAXC; q += 64) r1[q] = -1.0f;
    for (int q = min(c2, MAXC) + lane; q < MAXC; q += 64) r2[q] = -1.0f;
    for (int q = min(c3, MAXC) + lane; q < MAXC; q += 64) r3[q] = -1.0f;
  }
}

// ---------------------------------------------------------------------------
extern "C" void kernel_launch(void* const* d_in, const int* in_sizes, int n_in,
                              void* d_out, int out_size, void* d_ws,
                              size_t ws_size, hipStream_t stream) {
  const float* locs = (const float*)d_in[0];  // [2,4096,3]
  const float* data = (const float*)d_in[1];  // [2,4096,16]

  float* out = (float*)d_out;
  float* out_idxs = out;                                      // [2,4096]
  float* out_nbr = out + NBATCH * NPART;                      // [2,4096,128]
  float* out_locs = out_nbr + (size_t)NBATCH * NPART * MAXC;  // [2,4096,3]
  float* out_data = out_locs + (size_t)NBATCH * NPART * 3;    // [2,4096,16]

  // Workspace layout (bytes):
  //   pmin  f32[96]    @ 0      (384)
  //   pmax  f32[96]    @ 384    (768)
  //   cell_ids i32[8192] @ 768     (ends 33536)
  //   rank     i32[8192] @ 33536   (ends 66304)
  //   slocs  float4[8192] @ 66304  (16B aligned; ends 197376)
  float* pmin = (float*)d_ws;
  float* pmax = (float*)((char*)d_ws + 384);
  int* cell_ids = (int*)((char*)d_ws + 768);
  int* rank = (int*)((char*)d_ws + 768 + NBATCH * NPART * 4);
  float4* slocs = (float4*)((char*)d_ws + 768 + 2 * NBATCH * NPART * 4);

  void* args[] = {(void*)&locs,     (void*)&data,    (void*)&out_idxs,
                  (void*)&out_nbr,  (void*)&out_locs, (void*)&out_data,
                  (void*)&pmin,     (void*)&pmax,    (void*)&cell_ids,
                  (void*)&rank,     (void*)&slocs};
  hipLaunchCooperativeKernel(fused_kernel, dim3(NBLK), dim3(256), args, 0,
                             stream);
}

// Round 6
// 91.164 us; speedup vs baseline: 3.3451x; 3.3451x over previous
//
#include <hip/hip_runtime.h>

#define NPART 4096
#define NBATCH 2
#define MAXC 128

// ---------------------------------------------------------------------------
// Kernel 1: fused bounds + cell-id + stable-rank partial counts.
// Grid: NBATCH * 16 * NJ blocks; block (b, ic, jslice) covers i-chunk ic
// (256 particles) vs jspan j-chunks. Each block redundantly reduces its
// batch's min/max (fminf/fmaxf are order-independent -> bit-identical) and
// replays the verified f32 bounds math, then computes cell ids inline.
// Partial counts are written non-atomically as u16 slices (no zeroing dep).
// ---------------------------------------------------------------------------
__global__ __launch_bounds__(256) void rank_kernel(
    const float* __restrict__ locs, unsigned short* __restrict__ partial,
    int njlog2, int jspan) {
  const int bx = blockIdx.x;
  const int tid = threadIdx.x;
  const int jslice = bx & ((1 << njlog2) - 1);
  const int ic = (bx >> njlog2) & 15;
  const int b = bx >> (njlog2 + 4);

  __shared__ float smn[3][256];
  __shared__ float smx[3][256];
  __shared__ int scj[256];
  __shared__ float sb_lower[3];
  __shared__ int sb_gdi[3];

  const float* base = locs + (size_t)b * NPART * 3;
  // --- full-batch min/max reduce (verified pattern from R4 bounds) ---
  float mn0 = 1e30f, mn1 = 1e30f, mn2 = 1e30f;
  float mx0 = -1e30f, mx1 = -1e30f, mx2 = -1e30f;
  for (int n = tid; n < NPART; n += 256) {
    float x = base[n * 3 + 0];
    float y = base[n * 3 + 1];
    float z = base[n * 3 + 2];
    mn0 = fminf(mn0, x); mx0 = fmaxf(mx0, x);
    mn1 = fminf(mn1, y); mx1 = fmaxf(mx1, y);
    mn2 = fminf(mn2, z); mx2 = fmaxf(mx2, z);
  }
  smn[0][tid] = mn0; smn[1][tid] = mn1; smn[2][tid] = mn2;
  smx[0][tid] = mx0; smx[1][tid] = mx1; smx[2][tid] = mx2;
  __syncthreads();
  for (int s = 128; s > 0; s >>= 1) {
    if (tid < s) {
      for (int d = 0; d < 3; d++) {
        smn[d][tid] = fminf(smn[d][tid], smn[d][tid + s]);
        smx[d][tid] = fmaxf(smx[d][tid], smx[d][tid + s]);
      }
    }
    __syncthreads();
  }
  if (tid == 0) {
    for (int d = 0; d < 3; d++) {
      float lo = smn[d][0];
      float up = smx[d][0];
      float t = (up - lo) / 0.1f;               // fp32 IEEE div
      t = fminf(fmaxf(t, 0.0f), 96.0f);         // clip to [0, MAX_GRID_DIM]
      float gdim = ceilf(t);
      float ctr = (lo + up) * 0.5f;
      float l2 = ctr - ((gdim * 0.1f) * 0.5f);  // center - grid_dims*R*0.5
      float g = fmaxf(gdim, 1.0f);
      sb_lower[d] = l2;
      sb_gdi[d] = (int)g;
    }
  }
  __syncthreads();

  // --- cell id helper (verified f32 schedule) ---
  auto cid = [&](int n) {
    int c[3];
    for (int d = 0; d < 3; d++) {
      float v = base[n * 3 + d];
      float cf = floorf((v - sb_lower[d]) / 0.1f);
      float gdf = (float)sb_gdi[d];
      cf = fminf(fmaxf(cf, 0.0f), gdf - 1.0f);
      c[d] = (int)cf;
    }
    return (c[0] * sb_gdi[1] + c[1]) * sb_gdi[2] + c[2];
  };

  const int ci = cid(ic * 256 + tid);
  int cnt = 0;
  for (int jj = 0; jj < jspan; jj++) {
    int jc = jslice * jspan + jj;
    __syncthreads();
    scj[tid] = cid(jc * 256 + tid);
    __syncthreads();
    if (jc < ic) {
#pragma unroll 8
      for (int j = 0; j < 256; j++) cnt += (scj[j] <= ci);
    } else if (jc > ic) {
#pragma unroll 8
      for (int j = 0; j < 256; j++) cnt += (scj[j] < ci);
    } else {
#pragma unroll 8
      for (int j = 0; j < 256; j++) {
        int cj = scj[j];
        cnt += (cj < ci) || (cj == ci && j < tid);
      }
    }
  }
  partial[(size_t)jslice * (NBATCH * NPART) + b * NPART + ic * 256 + tid] =
      (unsigned short)cnt;
}

// ---------------------------------------------------------------------------
// Kernel 2: sum rank partials -> r; scatter idxs/locs_s/data_s/slocs at r.
// Thread owns ORIGINAL particle p; integer sum in fixed order (exact).
// sq = (x*x + y*y) + z*z rn mul/add (numpy materializes l*l first: no fma).
// ---------------------------------------------------------------------------
__global__ __launch_bounds__(256) void scatgather_kernel(
    const float* __restrict__ locs, const float* __restrict__ data,
    const unsigned short* __restrict__ partial, int nj,
    float* __restrict__ out_idxs, float* __restrict__ out_locs,
    float* __restrict__ out_data, float4* __restrict__ slocs) {
  int p = blockIdx.x * 256 + threadIdx.x;  // [0, NBATCH*NPART)
  int pb = p >> 12;
  int i = p & (NPART - 1);
  int r = 0;
  for (int s = 0; s < nj; s++)
    r += (int)partial[(size_t)s * (NBATCH * NPART) + p];
  const float* src = locs + (size_t)p * 3;
  float x = src[0], y = src[1], z = src[2];
  float sq = __fadd_rn(__fadd_rn(__fmul_rn(x, x), __fmul_rn(y, y)),
                       __fmul_rn(z, z));
  size_t dst = (size_t)pb * NPART + r;
  out_idxs[dst] = (float)i;
  out_locs[dst * 3 + 0] = x;
  out_locs[dst * 3 + 1] = y;
  out_locs[dst * 3 + 2] = z;
  slocs[dst] = make_float4(x, y, z, sq);
  const float4* dsrc = (const float4*)(data + (size_t)p * 16);
  float4* ddst = (float4*)(out_data + dst * 16);
  for (int k = 0; k < 4; k++) ddst[k] = dsrc[k];
}

// ---------------------------------------------------------------------------
// Kernel 3: neighbor lists. 8 rows/block, 2 rows/wave (2 independent ballot
// chains per ds_read), 32 KB LDS staged in 2 halves -> 4-5 blocks/CU.
//   dot = fma(z*z', fma(y*y', rn(x*x')))   (verified bit-exact)
//   d2  = rn(sq_n + sq_m) - rn(2*dot); hit = d2 <= 0.01f
// Ordered append via ballot + prefix popcount; -1 padding to MAXC.
// No early break (keeps __syncthreads convergent across the half loop).
// ---------------------------------------------------------------------------
__global__ __launch_bounds__(256) void nbr_kernel(
    const float4* __restrict__ slocs, float* __restrict__ out_nbr) {
  int b = blockIdx.y;
  __shared__ float4 sl[2048];  // 32 KB
  int wave = threadIdx.x >> 6, lane = threadIdx.x & 63;
  int row0 = blockIdx.x * 8 + wave * 2;
  const float4* sb = slocs + (size_t)b * NPART;
  float4 me0 = sb[row0 + 0];
  float4 me1 = sb[row0 + 1];
  float* r0 = out_nbr + ((size_t)b * NPART + row0) * MAXC;
  float* r1 = r0 + MAXC;
  int c0 = 0, c1 = 0;
  unsigned long long lmask = (1ull << lane) - 1ull;
  for (int half = 0; half < 2; half++) {
    int hbase = half * 2048;
    __syncthreads();
    for (int j = threadIdx.x; j < 2048; j += 256) sl[j] = sb[hbase + j];
    __syncthreads();
    for (int base = 0; base < 2048; base += 64) {
      float4 o = sl[base + lane];
      float fm = (float)(hbase + base + lane);
#define DO_ROW(ME, CN, RP)                                                  \
      {                                                                     \
        float dot = __fmaf_rn(ME.z, o.z,                                    \
                     __fmaf_rn(ME.y, o.y, __fmul_rn(ME.x, o.x)));           \
        float d2 = __fsub_rn(__fadd_rn(ME.w, o.w), __fmul_rn(2.0f, dot));   \
        bool hit = d2 <= 0.01f;                                             \
        unsigned long long bal = __ballot(hit);                             \
        int pos = CN + __popcll(bal & lmask);                               \
        if (hit && pos < MAXC) RP[pos] = fm;                                \
        CN += __popcll(bal);                                                \
      }
      DO_ROW(me0, c0, r0)
      DO_ROW(me1, c1, r1)
#undef DO_ROW
    }
  }
  for (int q = min(c0, MAXC) + lane; q < MAXC; q += 64) r0[q] = -1.0f;
  for (int q = min(c1, MAXC) + lane; q < MAXC; q += 64) r1[q] = -1.0f;
}

// ---------------------------------------------------------------------------
extern "C" void kernel_launch(void* const* d_in, const int* in_sizes, int n_in,
                              void* d_out, int out_size, void* d_ws,
                              size_t ws_size, hipStream_t stream) {
  const float* locs = (const float*)d_in[0];  // [2,4096,3]
  const float* data = (const float*)d_in[1];  // [2,4096,16]

  float* out = (float*)d_out;
  float* out_idxs = out;                                      // [2,4096]
  float* out_nbr = out + NBATCH * NPART;                      // [2,4096,128]
  float* out_locs = out_nbr + (size_t)NBATCH * NPART * MAXC;  // [2,4096,3]
  float* out_data = out_locs + (size_t)NBATCH * NPART * 3;    // [2,4096,16]

  // Workspace: slocs float4[8192] @ 0 (128 KB), partial u16[NJ*8192] after.
  float4* slocs = (float4*)d_ws;
  unsigned short* partial =
      (unsigned short*)((char*)d_ws + (size_t)NBATCH * NPART * 16);

  // NJ slices of non-atomic partial counts. Prefer 16 (512 blocks, 256 KB);
  // fall back to 4 (128 blocks, 64 KB) if ws is small. ws_size is constant
  // across calls -> branch is graph-capture-safe.
  size_t base_bytes = (size_t)NBATCH * NPART * 16;
  int nj, njlog2;
  if (ws_size >= base_bytes + 16ull * NBATCH * NPART * 2) {
    nj = 16; njlog2 = 4;
  } else {
    nj = 4; njlog2 = 2;
  }
  int jspan = 16 / nj;

  rank_kernel<<<NBATCH * 16 * nj, 256, 0, stream>>>(locs, partial, njlog2,
                                                    jspan);
  scatgather_kernel<<<NBATCH * NPART / 256, 256, 0, stream>>>(
      locs, data, partial, nj, out_idxs, out_locs, out_data, slocs);
  nbr_kernel<<<dim3(NPART / 8, NBATCH), 256, 0, stream>>>(slocs, out_nbr);
}